// Round 8
// baseline (238.102 us; speedup 1.0000x reference)
//
#include <hip/hip_runtime.h>

// ---------------------------------------------------------------------------
// Devault_Single_CCNN: only the LAST timestep feeds the head -> compute only
// the causal receptive field. Every layer is a stride-2 kernel-5 conv in
// index space: Out[q] = sum_k W[k] In[2q+k], lengths 509->253->125->61->29->
// 13->5->1. bf16 MFMA 16x16x32, fp32 accumulate. 2 dispatches:
//   k_prep : [0,112) weight-norm + MFMA-B pre-swizzle; [112,..) embedding
//            gather -> In0 [64][520][320] bf16 (massive TLP, coalesced).
//   k_net  : whole network per batch item. 64 blocks x 1024 thr (16 waves).
//            L0 in 4 qt-chunks (stage In0 slice -> LDS, MFMA, A0 -> swizzled
//            LDS, no global round-trip), then L1..L6 (conv_rest) + FC head.
// Masking invariant: MFMA C-row m depends only on A-row m, so garbage rows
// feed only outputs never read downstream. All LDS overreads stay inside the
// single lds[] allocation; all garbage values are finite.
// ---------------------------------------------------------------------------

typedef __attribute__((ext_vector_type(8))) short bfrag8;   // 8 bf16
typedef __attribute__((ext_vector_type(4))) float floatx4;  // MFMA acc
typedef __attribute__((ext_vector_type(4))) short short4v;
typedef __attribute__((ext_vector_type(4))) float float4v;

__device__ __forceinline__ unsigned short f2bf(float f) {
  union { float f; unsigned u; } v; v.f = f;
  unsigned r = v.u + 0x7fffu + ((v.u >> 16) & 1u);  // RNE
  return (unsigned short)(r >> 16);
}
__device__ __forceinline__ float bf2f(unsigned short h) {
  union { unsigned u; float f; } v; v.u = ((unsigned)h) << 16;
  return v.f;
}
__device__ __forceinline__ int swz(int row) { return ((row >> 1) & 7) << 4; }

// ---------------------------------------------------------------------------
// k_prep: blocks [0,112) weight-norm (one wave per o, butterfly reduce);
//         blocks [112,2672) gather emb -> In0 (pitch 640B, 520 rows,
//         rows>=509 and ch>=300 zeroed).
// WB layout: WB[((ot*NKS + ks)*64 + lane)*8 + i], lane=(o&15)|(kg<<4),
//            kk = ks*32 + kg*8 + i, kk = tap*CPAD + c (CPAD0=320, c>=300 -> 0)
// ---------------------------------------------------------------------------
__global__ __launch_bounds__(512)
void k_prep(const float* __restrict__ v0, const float* __restrict__ g0,
            const float* __restrict__ vr, const float* __restrict__ gr,
            const int* __restrict__ tokens, const float* __restrict__ emb,
            unsigned short* __restrict__ WB0, unsigned short* __restrict__ WBr,
            unsigned short* __restrict__ In0) {
  const int blk = blockIdx.x;
  if (blk >= 112) {                      // ---------- gather ----------
    const int gidx = ((blk - 112) << 9) + threadIdx.x;
    const int TOT = 64 * 520 * 80;       // 8B-chunks
    for (int idx = gidx; idx < TOT; idx += 2560 * 512) {
      const int c8 = idx % 80;
      const int rem = idx / 80;
      const int p = rem % 520;
      const int b = rem / 520;
      short4v o = {0, 0, 0, 0};
      if (p < 509 && c8 < 75) {
        const int tok = tokens[(b << 11) + 1539 + p];    // time = T-509+p
        const float4v v = *(const float4v*)(emb + (size_t)tok * 300 + (c8 << 2));
        o[0] = (short)f2bf(v[0]); o[1] = (short)f2bf(v[1]);
        o[2] = (short)f2bf(v[2]); o[3] = (short)f2bf(v[3]);
      }
      *(short4v*)(In0 + ((size_t)b * 520 + p) * 320 + (c8 << 2)) = o;
    }
    return;
  }
  // ---------- weight-norm ----------
  const int gw = (blk << 3) + (threadIdx.x >> 6);        // 0..895
  const int lane = threadIdx.x & 63;
  if (gw < 128) {                        // layer 0: K=1500 -> pad 1600
    const int o = gw;
    const float* v = v0 + o * 1500;
    float ss = 0.f;
    for (int i = lane; i < 1500; i += 64) { const float x = v[i]; ss += x * x; }
#pragma unroll
    for (int off = 32; off; off >>= 1) ss += __shfl_xor(ss, off, 64);
    const float scale = g0[o] * rsqrtf(ss);
    const int ot = o >> 4;
    for (int kk = lane; kk < 1600; kk += 64) {
      const int tap = kk / 320, c = kk % 320;
      const float w = (c < 300) ? v[c * 5 + tap] * scale : 0.f;
      const int ks = kk >> 5;
      const int li = (o & 15) | (((kk >> 3) & 3) << 4);
      WB0[(((ot * 50 + ks) * 64 + li) << 3) | (kk & 7)] = f2bf(w);
    }
  } else {                               // layers 1..6: K=640
    const int idx = gw - 128;
    const int l = idx >> 7, o = idx & 127;
    const float* v = vr + (size_t)(l * 128 + o) * 640;
    float ss = 0.f;
#pragma unroll
    for (int i = 0; i < 10; ++i) { const float x = v[lane + (i << 6)]; ss += x * x; }
#pragma unroll
    for (int off = 32; off; off >>= 1) ss += __shfl_xor(ss, off, 64);
    const float scale = gr[l * 128 + o] * rsqrtf(ss);
    unsigned short* WB = WBr + (size_t)l * 81920;
    const int ot = o >> 4;
#pragma unroll
    for (int i = 0; i < 10; ++i) {
      const int kk = lane + (i << 6);
      const int tap = kk >> 7, c = kk & 127;
      const float w = v[c * 5 + tap] * scale;
      const int ks = kk >> 5;
      const int li = (o & 15) | (((kk >> 3) & 3) << 4);
      WB[(((ot * 20 + ks) * 64 + li) << 3) | (kk & 7)] = f2bf(w);
    }
  }
}

// ---------------------------------------------------------------------------
// conv_rest (validated r5-r7): wave tile NMTW x NOTW, B preloaded per-quarter
// into VGPR arrays (static idx), A from swizzled 256B-pitch LDS. Stores
// unconditional; garbage rows finite + masked downstream.
// ---------------------------------------------------------------------------
template<int NMTW, int NOTW, int MTILES>
__device__ __forceinline__ void conv_rest(const char* bi, char* bo,
    const unsigned short* __restrict__ WBl, const float* __restrict__ bias,
    int w, int qb, int kg, int lane) {
  constexpr int NG = MTILES / NMTW;
  const int mg = (NG == 1) ? 0 : (w % NG);
  const int og = (NG == 1) ? w : (w / NG);
  if (og >= 8 / NOTW) return;
  floatx4 acc[NMTW][NOTW];
#pragma unroll
  for (int m = 0; m < NMTW; ++m)
#pragma unroll
    for (int j = 0; j < NOTW; ++j) acc[m][j] = floatx4{0.f, 0.f, 0.f, 0.f};
#pragma unroll
  for (int quarter = 0; quarter < 4; ++quarter) {
    bfrag8 bfs[NOTW][5];
#pragma unroll
    for (int j = 0; j < NOTW; ++j)
#pragma unroll
      for (int t = 0; t < 5; ++t)
        bfs[j][t] = *(const bfrag8*)(WBl +
            (size_t)(((((og * NOTW + j) * 20) + quarter * 5 + t) << 6) + lane) * 8);
#pragma unroll
    for (int t = 0; t < 5; ++t) {
      const int ks = quarter * 5 + t, tap = ks >> 2, cs = ks & 3;
#pragma unroll
      for (int m = 0; m < NMTW; ++m) {
        const int row = (((((mg * NMTW + m) << 4) + qb)) << 1) + tap;
        const int byte = ((row << 8) + (cs << 6) + (kg << 4)) ^ swz(row);
        const bfrag8 a = *(const bfrag8*)(bi + byte);
#pragma unroll
        for (int j = 0; j < NOTW; ++j)
          acc[m][j] = __builtin_amdgcn_mfma_f32_16x16x32_bf16(a, bfs[j][t], acc[m][j], 0, 0, 0);
      }
    }
  }
#pragma unroll
  for (int m = 0; m < NMTW; ++m)
#pragma unroll
    for (int j = 0; j < NOTW; ++j) {
      const int o = ((og * NOTW + j) << 4) + qb;
      const float bv = bias[o];
#pragma unroll
      for (int r = 0; r < 4; ++r) {
        const int qq = ((mg * NMTW + m) << 4) + (kg << 2) + r;
        const int byte2 = ((qq << 8) + (o << 1)) ^ swz(qq);
        *(unsigned short*)(bo + byte2) = f2bf(fmaxf(acc[m][j][r] + bv, 0.f));
      }
    }
}

// ---------------------------------------------------------------------------
// k_net: the whole network for one batch item. 64 blocks x 1024 thr (16 waves)
// LDS map (single alloc, 152,880 B):
//   [0,85936)        embChunk 131 x 656   (L0 staging; dead after L0)
//     overlay: actP at 0 (131-row slack), actQ at 33536 (67-row slack)
//   [85936,152496)   bufIn (A0) 260 rows x 256B, swizzled
//   [152496,152880)  h1[64], h2[32]
// L0: 4 chunks; wave w: og=w&3 (ot pair), mg=w>>2 (m-tile). Writes A0 rows
// 64qt+0..63 to bufIn. Rows >=253: convolved zeros -> finite, masked later.
// ---------------------------------------------------------------------------
__global__ __launch_bounds__(1024, 1)
void k_net(const unsigned short* __restrict__ In0,
           const unsigned short* __restrict__ WB0, const unsigned short* __restrict__ WBr,
           const float* __restrict__ b0, const float* __restrict__ br,
           const float* __restrict__ de,
           const float* __restrict__ w1, const float* __restrict__ b1,
           const float* __restrict__ w2, const float* __restrict__ b2,
           const float* __restrict__ w3, const float* __restrict__ b3,
           float* __restrict__ out) {
  __shared__ char lds[152880];
  char* embChunk = lds;
  char* actP = lds;
  char* actQ = lds + 33536;
  char* bufIn = lds + 85936;
  float* h1 = (float*)(lds + 152496);
  float* h2 = h1 + 64;
  const int tid = threadIdx.x, b = blockIdx.x;
  const int lane = tid & 63, w = tid >> 6;
  const int qb = lane & 15, kg = lane >> 4;
  const int og = w & 3, mg = w >> 2;

  // ================= L0: 4 chunks of 64 output rows =================
  const unsigned short* wb0 = WB0 + (size_t)((((og << 1) * 50) << 6) + lane) * 8;
  const int arow = ((mg << 4) + qb) << 1;
  const int o0 = (og << 5) + qb;
  const float bv0 = b0[o0], bv1 = b0[o0 + 16];
  for (int qt = 0; qt < 4; ++qt) {
    // stage In0 rows [128qt, 128qt+130] (pitch 640 -> LDS pitch 656)
    const char* src = (const char*)(In0 + ((size_t)b * 520 + (qt << 7)) * 320);
    for (int idx = tid; idx < 131 * 41; idx += 1024) {
      const int r = idx / 41, s = idx - r * 41;
      float4v v = {0.f, 0.f, 0.f, 0.f};
      if (s < 40) v = *(const float4v*)(src + r * 640 + (s << 4));
      *(float4v*)(embChunk + r * 656 + (s << 4)) = v;
    }
    __syncthreads();
    floatx4 acc0 = {0.f, 0.f, 0.f, 0.f}, acc1 = {0.f, 0.f, 0.f, 0.f};
#pragma unroll
    for (int tap = 0; tap < 5; ++tap) {
#pragma unroll
      for (int h = 0; h < 2; ++h) {
        bfrag8 bf0[5], bf1[5];
#pragma unroll
        for (int j = 0; j < 5; ++j) {
          const int ks = tap * 10 + h * 5 + j;
          bf0[j] = *(const bfrag8*)(wb0 + (ks << 9));
          bf1[j] = *(const bfrag8*)(wb0 + ((ks + 50) << 9));
        }
#pragma unroll
        for (int j = 0; j < 5; ++j) {
          const int cb = (((h * 5 + j) << 6)) + (kg << 4);
          const bfrag8 a = *(const bfrag8*)(embChunk + (arow + tap) * 656 + cb);
          acc0 = __builtin_amdgcn_mfma_f32_16x16x32_bf16(a, bf0[j], acc0, 0, 0, 0);
          acc1 = __builtin_amdgcn_mfma_f32_16x16x32_bf16(a, bf1[j], acc1, 0, 0, 0);
        }
      }
    }
#pragma unroll
    for (int r = 0; r < 4; ++r) {
      const int qq = (qt << 6) + (mg << 4) + (kg << 2) + r;
      *(unsigned short*)(bufIn + (((qq << 8) + (o0 << 1)) ^ swz(qq))) =
          f2bf(fmaxf(acc0[r] + bv0, 0.f));
      *(unsigned short*)(bufIn + (((qq << 8) + ((o0 + 16) << 1)) ^ swz(qq))) =
          f2bf(fmaxf(acc1[r] + bv1, 0.f));
    }
    __syncthreads();   // compute done before next chunk overwrites embChunk
  }

  // ================= L1..L6 =================
  conv_rest<2, 2, 8>(bufIn, actP, WBr + 0 * 81920, br + 0,   w, qb, kg, lane); // M=125
  __syncthreads();
  conv_rest<1, 2, 4>(actP, actQ, WBr + 1 * 81920, br + 128, w, qb, kg, lane);  // M=61
  __syncthreads();
  conv_rest<1, 1, 2>(actQ, actP, WBr + 2 * 81920, br + 256, w, qb, kg, lane);  // M=29
  __syncthreads();
  conv_rest<1, 1, 1>(actP, actQ, WBr + 3 * 81920, br + 384, w, qb, kg, lane);  // M=13
  __syncthreads();
  conv_rest<1, 1, 1>(actQ, actP, WBr + 4 * 81920, br + 512, w, qb, kg, lane);  // M=5
  __syncthreads();
  conv_rest<1, 1, 1>(actP, actQ, WBr + 5 * 81920, br + 640, w, qb, kg, lane);  // M=1
  __syncthreads();

  // ================= head: [actQ row 0 (swz identity), de] -> 64 -> 32 -> 1
  const unsigned short* o6 = (const unsigned short*)actQ;
  if (tid < 512) {                       // h1: 64 outs x 8 threads
    const int o1 = tid >> 3, part = tid & 7;
    const int j0 = part * 18;
    const int j1 = (j0 + 18 < 139) ? j0 + 18 : 139;
    float s = 0.f;
    const float* wrow = w1 + o1 * 139;
    for (int j = j0; j < j1; ++j) {
      const float x = (j < 128) ? bf2f(o6[j]) : de[b * 11 + (j - 128)];
      s += wrow[j] * x;
    }
    s += __shfl_down(s, 4, 64);
    s += __shfl_down(s, 2, 64);
    s += __shfl_down(s, 1, 64);
    if (part == 0) h1[o1] = fmaxf(s + b1[o1], 0.f);
  }
  __syncthreads();
  if (tid < 64) {                        // h2: 32 outs x 2 threads
    const int o2 = tid >> 1, part = tid & 1;
    float s = 0.f;
    const float* wrow = w2 + o2 * 64 + part * 32;
    for (int j = 0; j < 32; ++j) s += wrow[j] * h1[part * 32 + j];
    s += __shfl_down(s, 1, 64);
    if (part == 0) h2[o2] = fmaxf(s + b2[o2], 0.f);
  }
  __syncthreads();
  if (tid < 32) {
    float s = w3[tid] * h2[tid];
    s += __shfl_down(s, 16, 64);
    s += __shfl_down(s, 8, 64);
    s += __shfl_down(s, 4, 64);
    s += __shfl_down(s, 2, 64);
    s += __shfl_down(s, 1, 64);
    if (tid == 0) out[b] = s + b3[0];
  }
}

// ---------------------------------------------------------------------------
extern "C" void kernel_launch(void* const* d_in, const int* in_sizes, int n_in,
                              void* d_out, int out_size, void* d_ws, size_t ws_size,
                              hipStream_t stream) {
  const int*   tokens = (const int*)  d_in[0];
  const float* de     = (const float*)d_in[1];
  const float* emb    = (const float*)d_in[2];
  const float* v0     = (const float*)d_in[3];
  const float* g0     = (const float*)d_in[4];
  const float* b0     = (const float*)d_in[5];
  const float* vr     = (const float*)d_in[6];
  const float* gr     = (const float*)d_in[7];
  const float* br     = (const float*)d_in[8];
  const float* w1     = (const float*)d_in[9];
  const float* b1     = (const float*)d_in[10];
  const float* w2     = (const float*)d_in[11];
  const float* b2     = (const float*)d_in[12];
  const float* w3     = (const float*)d_in[13];
  const float* b3     = (const float*)d_in[14];
  float* out = (float*)d_out;

  char* w = (char*)d_ws;
  unsigned short* WB0 = (unsigned short*)(w + 0);          // 128x1600 bf16
  unsigned short* WBr = (unsigned short*)(w + 409600);     // 6 x 128x640 bf16
  unsigned short* In0 = (unsigned short*)(w + 1392640);    // [64][520][320] bf16

  hipLaunchKernelGGL(k_prep, dim3(112 + 2560), dim3(512), 0, stream,
                     v0, g0, vr, gr, tokens, emb, WB0, WBr, In0);
  hipLaunchKernelGGL(k_net, dim3(64), dim3(1024), 0, stream,
                     In0, WB0, WBr, b0, br, de, w1, b1, w2, b2, w3, b3, out);
}

// Round 9
// 66.526 us; speedup vs baseline: 3.5791x; 3.5791x over previous
//
#include <hip/hip_runtime.h>

// ---------------------------------------------------------------------------
// Devault_Single_CCNN: only the LAST timestep feeds the head -> compute only
// the causal receptive field. Every layer is a stride-2 kernel-5 conv in
// index space: Out[q] = sum_k W[k] In[2q+k], lengths 509->253->125->61->29->
// 13->5->1. bf16 MFMA 16x16x32, fp32 accumulate. 4 dispatches:
//   k_prep : [0,112) weight-norm + B pre-swizzle; [112,..) emb gather -> In0.
//   k_conv0: L0. (4qt x 64b) x 512 thr, VGPR-rich (no spill class: r6=152).
//   k_conv1: L1. (4qt x 64b) x 512 thr, 1m x 2ot per wave, 17KB LDS.
//   k_tail2: L2..L6 + head. 64 x 512 thr, bounded per-tap B preloads.
// r8 lesson: 1024-thr kernels get VGPR-capped at 64 -> scratch spill (171MB
// FETCH). All kernels here are 512-thr with bounded register arrays.
// Masking invariant: MFMA C-row m depends only on A-row m; garbage rows are
// finite and feed only outputs never read downstream.
// ---------------------------------------------------------------------------

typedef __attribute__((ext_vector_type(8))) short bfrag8;   // 8 bf16
typedef __attribute__((ext_vector_type(4))) float floatx4;  // MFMA acc
typedef __attribute__((ext_vector_type(4))) short short4v;
typedef __attribute__((ext_vector_type(4))) float float4v;

__device__ __forceinline__ unsigned short f2bf(float f) {
  union { float f; unsigned u; } v; v.f = f;
  unsigned r = v.u + 0x7fffu + ((v.u >> 16) & 1u);  // RNE
  return (unsigned short)(r >> 16);
}
__device__ __forceinline__ float bf2f(unsigned short h) {
  union { unsigned u; float f; } v; v.u = ((unsigned)h) << 16;
  return v.f;
}
__device__ __forceinline__ int swz(int row) { return ((row >> 1) & 7) << 4; }

// ---------------------------------------------------------------------------
// k_prep: blocks [0,112) weight-norm (one wave per o, butterfly reduce);
//         blocks [112,2672) gather emb -> In0 (pitch 640B, 520 rows,
//         rows>=509 and ch>=300 zeroed).
// WB layout: WB[((ot*NKS + ks)*64 + lane)*8 + i], lane=(o&15)|(kg<<4),
//            kk = ks*32 + kg*8 + i, kk = tap*CPAD + c (CPAD0=320, c>=300 -> 0)
// ---------------------------------------------------------------------------
__global__ __launch_bounds__(512)
void k_prep(const float* __restrict__ v0, const float* __restrict__ g0,
            const float* __restrict__ vr, const float* __restrict__ gr,
            const int* __restrict__ tokens, const float* __restrict__ emb,
            unsigned short* __restrict__ WB0, unsigned short* __restrict__ WBr,
            unsigned short* __restrict__ In0) {
  const int blk = blockIdx.x;
  if (blk >= 112) {                      // ---------- gather ----------
    const int gidx = ((blk - 112) << 9) + threadIdx.x;
    const int TOT = 64 * 520 * 80;       // 8B-chunks
    for (int idx = gidx; idx < TOT; idx += 2560 * 512) {
      const int c8 = idx % 80;
      const int rem = idx / 80;
      const int p = rem % 520;
      const int b = rem / 520;
      short4v o = {0, 0, 0, 0};
      if (p < 509 && c8 < 75) {
        const int tok = tokens[(b << 11) + 1539 + p];    // time = T-509+p
        const float4v v = *(const float4v*)(emb + (size_t)tok * 300 + (c8 << 2));
        o[0] = (short)f2bf(v[0]); o[1] = (short)f2bf(v[1]);
        o[2] = (short)f2bf(v[2]); o[3] = (short)f2bf(v[3]);
      }
      *(short4v*)(In0 + ((size_t)b * 520 + p) * 320 + (c8 << 2)) = o;
    }
    return;
  }
  // ---------- weight-norm ----------
  const int gw = (blk << 3) + (threadIdx.x >> 6);        // 0..895
  const int lane = threadIdx.x & 63;
  if (gw < 128) {                        // layer 0: K=1500 -> pad 1600
    const int o = gw;
    const float* v = v0 + o * 1500;
    float ss = 0.f;
    for (int i = lane; i < 1500; i += 64) { const float x = v[i]; ss += x * x; }
#pragma unroll
    for (int off = 32; off; off >>= 1) ss += __shfl_xor(ss, off, 64);
    const float scale = g0[o] * rsqrtf(ss);
    const int ot = o >> 4;
    for (int kk = lane; kk < 1600; kk += 64) {
      const int tap = kk / 320, c = kk % 320;
      const float w = (c < 300) ? v[c * 5 + tap] * scale : 0.f;
      const int ks = kk >> 5;
      const int li = (o & 15) | (((kk >> 3) & 3) << 4);
      WB0[(((ot * 50 + ks) * 64 + li) << 3) | (kk & 7)] = f2bf(w);
    }
  } else {                               // layers 1..6: K=640
    const int idx = gw - 128;
    const int l = idx >> 7, o = idx & 127;
    const float* v = vr + (size_t)(l * 128 + o) * 640;
    float ss = 0.f;
#pragma unroll
    for (int i = 0; i < 10; ++i) { const float x = v[lane + (i << 6)]; ss += x * x; }
#pragma unroll
    for (int off = 32; off; off >>= 1) ss += __shfl_xor(ss, off, 64);
    const float scale = gr[l * 128 + o] * rsqrtf(ss);
    unsigned short* WB = WBr + (size_t)l * 81920;
    const int ot = o >> 4;
#pragma unroll
    for (int i = 0; i < 10; ++i) {
      const int kk = lane + (i << 6);
      const int tap = kk >> 7, c = kk & 127;
      const float w = v[c * 5 + tap] * scale;
      const int ks = kk >> 5;
      const int li = (o & 15) | (((kk >> 3) & 3) << 4);
      WB[(((ot * 20 + ks) * 64 + li) << 3) | (kk & 7)] = f2bf(w);
    }
  }
}

// ---------------------------------------------------------------------------
// k_conv0: layer 0 (proven r7 structure, VGPR-rich). Grid (4qt, 64b) x 512.
// Stage In0 rows [128qt..128qt+130] into LDS pitch 656B (bank-optimal for
// step-2-row b128 reads). Wave w: og=w&3 (ot pair), mg=w>>2 (2 m-tiles).
// Writes A0 rows 64qt..64qt+63 (rows>=253 finite garbage, never read valid).
// ---------------------------------------------------------------------------
__global__ __launch_bounds__(512, 1)
void k_conv0(const unsigned short* __restrict__ In0,
             const unsigned short* __restrict__ WB, const float* __restrict__ b0,
             unsigned short* __restrict__ A0) {
  __shared__ char buf[131 * 656];
  const int tid = threadIdx.x;
  const int qt = blockIdx.x, b = blockIdx.y;
  const char* src = (const char*)(In0 + ((size_t)b * 520 + (qt << 7)) * 320);
  for (int idx = tid; idx < 131 * 41; idx += 512) {
    const int r = idx / 41, s = idx - r * 41;
    float4v v = {0.f, 0.f, 0.f, 0.f};
    if (s < 40) v = *(const float4v*)(src + r * 640 + (s << 4));
    *(float4v*)(buf + r * 656 + (s << 4)) = v;
  }
  __syncthreads();
  const int lane = tid & 63, w = tid >> 6;
  const int og = w & 3, mg = w >> 2;
  const int qb = lane & 15, kg = lane >> 4;
  floatx4 acc[2][2];
#pragma unroll
  for (int m = 0; m < 2; ++m) {
    acc[m][0] = floatx4{0.f, 0.f, 0.f, 0.f};
    acc[m][1] = floatx4{0.f, 0.f, 0.f, 0.f};
  }
  const unsigned short* wb0 = WB + (size_t)((((og << 1) * 50) << 6) + lane) * 8;
#pragma unroll
  for (int tap = 0; tap < 5; ++tap) {
    bfrag8 bf0[10], bf1[10];
#pragma unroll
    for (int cs = 0; cs < 10; ++cs) {
      const int ks = tap * 10 + cs;
      bf0[cs] = *(const bfrag8*)(wb0 + (ks << 9));
      bf1[cs] = *(const bfrag8*)(wb0 + ((ks + 50) << 9));
    }
#pragma unroll
    for (int cs = 0; cs < 10; ++cs) {
      const int cb = (cs << 6) + (kg << 4);
#pragma unroll
      for (int m = 0; m < 2; ++m) {
        const int row = (((((mg << 1) + m) << 4) + qb) << 1) + tap;  // <=130
        const bfrag8 a = *(const bfrag8*)(buf + row * 656 + cb);
        acc[m][0] = __builtin_amdgcn_mfma_f32_16x16x32_bf16(a, bf0[cs], acc[m][0], 0, 0, 0);
        acc[m][1] = __builtin_amdgcn_mfma_f32_16x16x32_bf16(a, bf1[cs], acc[m][1], 0, 0, 0);
      }
    }
  }
  unsigned short* ob = A0 + (((size_t)b << 8) + (qt << 6)) * 128;
  const int o0 = (og << 5) + qb;
  const float bv0 = b0[o0], bv1 = b0[o0 + 16];
#pragma unroll
  for (int m = 0; m < 2; ++m)
#pragma unroll
    for (int r = 0; r < 4; ++r) {
      const int ql = ((((mg << 1) + m) << 4) + (kg << 2)) + r;       // 0..63
      ob[ql * 128 + o0]      = f2bf(fmaxf(acc[m][0][r] + bv0, 0.f));
      ob[ql * 128 + o0 + 16] = f2bf(fmaxf(acc[m][1][r] + bv1, 0.f));
    }
}

// ---------------------------------------------------------------------------
// k_conv1: layer 1. Grid (4qt, 64b) x 512 thr = 256 blocks (1/CU).
// Stage A0 rows [64qt..64qt+66] (clamped <=255) into 256B-pitch XOR-swizzled
// LDS. Wave w: og=w&3 (ot pair {2og,2og+1}), mg=w>>2 (one m-tile of 2).
// Per tap: 8 B-frag preloads (32 VGPR, bounded). Writes L1out rows
// 32qt..32qt+31 (valid <125; garbage finite, masked downstream).
// ---------------------------------------------------------------------------
__global__ __launch_bounds__(512, 1)
void k_conv1(const unsigned short* __restrict__ A0,
             const unsigned short* __restrict__ WBr, const float* __restrict__ br,
             unsigned short* __restrict__ L1out) {
  __shared__ char abuf[68 * 256];
  const int tid = threadIdx.x;
  const int qt = blockIdx.x, b = blockIdx.y;
  const char* a0b = (const char*)(A0 + ((size_t)b << 15));
  for (int idx = tid; idx < 67 * 16; idx += 512) {
    const int r = idx >> 4, s = idx & 15;
    int rs = (qt << 6) + r; if (rs > 255) rs = 255;       // clamp (garbage rows)
    *(float4v*)(abuf + (((r << 8) + (s << 4)) ^ swz(r))) =
        *(const float4v*)(a0b + (rs << 8) + (s << 4));
  }
  __syncthreads();
  const int lane = tid & 63, w = tid >> 6;
  const int og = w & 3, mg = w >> 2;
  const int qb = lane & 15, kg = lane >> 4;
  floatx4 acc0 = {0.f, 0.f, 0.f, 0.f}, acc1 = {0.f, 0.f, 0.f, 0.f};
  const unsigned short* wb = WBr + (size_t)((((og << 1) * 20) << 6) + lane) * 8;
#pragma unroll
  for (int tap = 0; tap < 5; ++tap) {
    bfrag8 bf0[4], bf1[4];
#pragma unroll
    for (int cs = 0; cs < 4; ++cs) {
      const int ks = (tap << 2) + cs;
      bf0[cs] = *(const bfrag8*)(wb + (ks << 9));
      bf1[cs] = *(const bfrag8*)(wb + ((ks + 20) << 9));
    }
#pragma unroll
    for (int cs = 0; cs < 4; ++cs) {
      const int cb = (cs << 6) + (kg << 4);
      const int row = (((mg << 4) + qb) << 1) + tap;      // <=66
      const bfrag8 a = *(const bfrag8*)(abuf + (((row << 8) + cb) ^ swz(row)));
      acc0 = __builtin_amdgcn_mfma_f32_16x16x32_bf16(a, bf0[cs], acc0, 0, 0, 0);
      acc1 = __builtin_amdgcn_mfma_f32_16x16x32_bf16(a, bf1[cs], acc1, 0, 0, 0);
    }
  }
  unsigned short* ob = L1out + (((size_t)b << 7) + (qt << 5)) * 128;
  const int o0 = (og << 5) + qb;
  const float bv0 = br[o0], bv1 = br[o0 + 16];
#pragma unroll
  for (int r = 0; r < 4; ++r) {
    const int ql = (mg << 4) + (kg << 2) + r;             // 0..31
    ob[ql * 128 + o0]      = f2bf(fmaxf(acc0[r] + bv0, 0.f));
    ob[ql * 128 + o0 + 16] = f2bf(fmaxf(acc1[r] + bv1, 0.f));
  }
}

// ---------------------------------------------------------------------------
// convT: wave tile NMTW x NOTW with per-tap B preload (NOTW*4 frags <= 8,
// bounded VGPR). A from swizzled 256B-pitch LDS. Stores unconditional;
// garbage rows finite + masked downstream.
// ---------------------------------------------------------------------------
template<int NMTW, int NOTW, int MTILES>
__device__ __forceinline__ void convT(const char* bi, char* bo,
    const unsigned short* __restrict__ WBl, const float* __restrict__ bias,
    int w, int qb, int kg, int lane) {
  constexpr int NMG = MTILES / NMTW;
  const int mg = (NMG == 1) ? 0 : (w % NMG);
  const int og = (NMG == 1) ? w : (w / NMG);
  if (og >= 8 / NOTW) return;
  floatx4 acc[NMTW][NOTW];
#pragma unroll
  for (int m = 0; m < NMTW; ++m)
#pragma unroll
    for (int j = 0; j < NOTW; ++j) acc[m][j] = floatx4{0.f, 0.f, 0.f, 0.f};
#pragma unroll
  for (int tap = 0; tap < 5; ++tap) {
    bfrag8 bfs[NOTW][4];
#pragma unroll
    for (int j = 0; j < NOTW; ++j)
#pragma unroll
      for (int cs = 0; cs < 4; ++cs)
        bfs[j][cs] = *(const bfrag8*)(WBl +
            (size_t)((((og * NOTW + j) * 20 + (tap << 2) + cs) << 6) + lane) * 8);
#pragma unroll
    for (int cs = 0; cs < 4; ++cs) {
      const int cb = (cs << 6) + (kg << 4);
#pragma unroll
      for (int m = 0; m < NMTW; ++m) {
        const int row = (((mg * NMTW + m) << 4) + qb) * 2 + tap;
        const bfrag8 a = *(const bfrag8*)(bi + (((row << 8) + cb) ^ swz(row)));
#pragma unroll
        for (int j = 0; j < NOTW; ++j)
          acc[m][j] = __builtin_amdgcn_mfma_f32_16x16x32_bf16(a, bfs[j][cs], acc[m][j], 0, 0, 0);
      }
    }
  }
#pragma unroll
  for (int m = 0; m < NMTW; ++m)
#pragma unroll
    for (int j = 0; j < NOTW; ++j) {
      const int o = ((og * NOTW + j) << 4) + qb;
      const float bv = bias[o];
#pragma unroll
      for (int r = 0; r < 4; ++r) {
        const int qq = ((mg * NMTW + m) << 4) + (kg << 2) + r;
        *(unsigned short*)(bo + (((qq << 8) + (o << 1)) ^ swz(qq))) =
            f2bf(fmaxf(acc[m][j][r] + bv, 0.f));
      }
    }
}

// ---------------------------------------------------------------------------
// k_tail2: 64 blocks x 512 thr. L2..L6 + head.
// bufA 136 rows (stage 128 + zeroed 128..135), bufB 72 rows (64..71 zeroed).
// Ping-pong A->B->A->B->A->B; head reads bufB row 0 (swz identity).
// All overreads hit zeroed or stale-finite LDS; valid chain reads valid only.
// ---------------------------------------------------------------------------
__global__ __launch_bounds__(512, 1)
void k_tail2(const unsigned short* __restrict__ L1out, const unsigned short* __restrict__ WBr,
             const float* __restrict__ br, const float* __restrict__ de,
             const float* __restrict__ w1, const float* __restrict__ b1,
             const float* __restrict__ w2, const float* __restrict__ b2,
             const float* __restrict__ w3, const float* __restrict__ b3,
             float* __restrict__ out) {
  __shared__ char lds[136 * 256 + 72 * 256 + 384];
  char* bufA = lds;
  char* bufB = lds + 136 * 256;
  float* h1 = (float*)(lds + 136 * 256 + 72 * 256);
  float* h2 = h1 + 64;
  const int tid = threadIdx.x, b = blockIdx.x;
  const int lane = tid & 63, w = tid >> 6;
  const int qb = lane & 15, kg = lane >> 4;

  // stage L1out rows 0..127 -> bufA (swizzled); zero bufA 128..135, bufB 64..71
  const char* l1b = (const char*)(L1out + ((size_t)b << 14));
  for (int idx = tid; idx < 136 * 16; idx += 512) {
    const int r = idx >> 4, s = idx & 15;
    float4v v = {0.f, 0.f, 0.f, 0.f};
    if (r < 128) v = *(const float4v*)(l1b + (r << 8) + (s << 4));
    *(float4v*)(bufA + (((r << 8) + (s << 4)) ^ swz(r))) = v;
  }
  for (int idx = tid; idx < 8 * 16; idx += 512) {
    const int r = 64 + (idx >> 4), s = idx & 15;
    *(float4v*)(bufB + (((r << 8) + (s << 4)) ^ swz(r))) = float4v{0.f, 0.f, 0.f, 0.f};
  }
  __syncthreads();

  convT<2, 2, 4>(bufA, bufB, WBr + 1 * 81920, br + 128, w, qb, kg, lane); // L2 M=61
  __syncthreads();
  convT<1, 2, 2>(bufB, bufA, WBr + 2 * 81920, br + 256, w, qb, kg, lane); // L3 M=29
  __syncthreads();
  convT<1, 1, 1>(bufA, bufB, WBr + 3 * 81920, br + 384, w, qb, kg, lane); // L4 M=13
  __syncthreads();
  convT<1, 1, 1>(bufB, bufA, WBr + 4 * 81920, br + 512, w, qb, kg, lane); // L5 M=5
  __syncthreads();
  convT<1, 1, 1>(bufA, bufB, WBr + 5 * 81920, br + 640, w, qb, kg, lane); // L6 M=1
  __syncthreads();

  // head: combo = [bufB row 0 (swz identity), de] -> 64 -> 32 -> 1
  const unsigned short* o6 = (const unsigned short*)bufB;
  {                                      // h1: 64 outs x 8 threads
    const int o1 = tid >> 3, part = tid & 7;
    const int j0 = part * 18;
    const int j1 = (j0 + 18 < 139) ? j0 + 18 : 139;
    float s = 0.f;
    const float* wrow = w1 + o1 * 139;
    for (int j = j0; j < j1; ++j) {
      const float x = (j < 128) ? bf2f(o6[j]) : de[b * 11 + (j - 128)];
      s += wrow[j] * x;
    }
    s += __shfl_down(s, 4, 64);
    s += __shfl_down(s, 2, 64);
    s += __shfl_down(s, 1, 64);
    if (part == 0) h1[o1] = fmaxf(s + b1[o1], 0.f);
  }
  __syncthreads();
  if (tid < 64) {                        // h2: 32 outs x 2 threads
    const int o2 = tid >> 1, part = tid & 1;
    float s = 0.f;
    const float* wrow = w2 + o2 * 64 + part * 32;
    for (int j = 0; j < 32; ++j) s += wrow[j] * h1[part * 32 + j];
    s += __shfl_down(s, 1, 64);
    if (part == 0) h2[o2] = fmaxf(s + b2[o2], 0.f);
  }
  __syncthreads();
  if (tid < 32) {
    float s = w3[tid] * h2[tid];
    s += __shfl_down(s, 16, 64);
    s += __shfl_down(s, 8, 64);
    s += __shfl_down(s, 4, 64);
    s += __shfl_down(s, 2, 64);
    s += __shfl_down(s, 1, 64);
    if (tid == 0) out[b] = s + b3[0];
  }
}

// ---------------------------------------------------------------------------
extern "C" void kernel_launch(void* const* d_in, const int* in_sizes, int n_in,
                              void* d_out, int out_size, void* d_ws, size_t ws_size,
                              hipStream_t stream) {
  const int*   tokens = (const int*)  d_in[0];
  const float* de     = (const float*)d_in[1];
  const float* emb    = (const float*)d_in[2];
  const float* v0     = (const float*)d_in[3];
  const float* g0     = (const float*)d_in[4];
  const float* b0     = (const float*)d_in[5];
  const float* vr     = (const float*)d_in[6];
  const float* gr     = (const float*)d_in[7];
  const float* br     = (const float*)d_in[8];
  const float* w1     = (const float*)d_in[9];
  const float* b1     = (const float*)d_in[10];
  const float* w2     = (const float*)d_in[11];
  const float* b2     = (const float*)d_in[12];
  const float* w3     = (const float*)d_in[13];
  const float* b3     = (const float*)d_in[14];
  float* out = (float*)d_out;

  char* w = (char*)d_ws;
  unsigned short* WB0   = (unsigned short*)(w + 0);        // 128x1600 bf16
  unsigned short* WBr   = (unsigned short*)(w + 409600);   // 6 x 128x640 bf16
  unsigned short* In0   = (unsigned short*)(w + 1392640);  // [64][520][320] bf16
  unsigned short* A0    = (unsigned short*)(w + 22691840); // [64][256][128] bf16
  unsigned short* L1out = (unsigned short*)(w + 26886144); // [64][128][128] bf16

  hipLaunchKernelGGL(k_prep, dim3(112 + 2560), dim3(512), 0, stream,
                     v0, g0, vr, gr, tokens, emb, WB0, WBr, In0);
  hipLaunchKernelGGL(k_conv0, dim3(4, 64), dim3(512), 0, stream, In0, WB0, b0, A0);
  hipLaunchKernelGGL(k_conv1, dim3(4, 64), dim3(512), 0, stream, A0, WBr, br, L1out);
  hipLaunchKernelGGL(k_tail2, dim3(64), dim3(512), 0, stream,
                     L1out, WBr, br, de, w1, b1, w2, b2, w3, b3, out);
}